// Round 1
// baseline (617.066 us; speedup 1.0000x reference)
//
#include <hip/hip_runtime.h>

#define BATCH 32
#define NLEN  1024
#define NUMV  (BATCH * NLEN)

// Fused GeneralConv layer for HC = H*COUT = 1024 layers (1..4).
// Block = 256 threads, owns TILE nodes of one graph + 1-node halo each side.
// phase 1: M[j][c] = leaky_relu(x[j]@Wm + bm) for TILE+2 nodes, alpha[j][h] = <M[j][h,:], att[h,:]>
// phase 2a: softmax weights over the <=2 incoming edges per node
// phase 2b: out = mean_h(w_p*M[prev] + w_n*M[next]) + x@Ws + bs (+ ELU)
template<int CIN, int COUT, int H, int TILE, bool DO_ELU>
__global__ __launch_bounds__(256, 2)
void conv_layer(const float* __restrict__ x,
                const float* __restrict__ Wm,
                const float* __restrict__ bm,
                const float* __restrict__ Ws,
                const float* __restrict__ bs,
                const float* __restrict__ att,
                float* __restrict__ y)
{
    constexpr int HC = H * COUT;
    static_assert(HC == 1024, "phase-1 mapping assumes HC==1024");
    constexpr int TPG = (NLEN + TILE - 1) / TILE;   // tiles per graph
    constexpr int RL  = COUT / 4;                   // lanes per head in phase 1

    const int tid = threadIdx.x;
    const int g   = blockIdx.x / TPG;
    const int t   = blockIdx.x % TPG;
    const int n0  = t * TILE;
    const int count = (NLEN - n0) < TILE ? (NLEN - n0) : TILE;

    extern __shared__ float lds[];
    float* xs = lds;                              // (TILE+2) * CIN
    float* ms = xs + (TILE + 2) * CIN;            // (TILE+2) * HC
    float* al = ms + (TILE + 2) * HC;             // (TILE+2) * H
    float* wp = al + (TILE + 2) * H;              // TILE * H
    float* wn = wp + TILE * H;                    // TILE * H

    const long base = (long)g * NLEN + n0 - 1;    // global node at local row j=0

    // ---- stage x tile (+halo) into LDS; zero-fill invalid rows ----
    for (int f = tid; f < (TILE + 2) * CIN; f += 256) {
        int j = f / CIN;
        int c = f - j * CIN;
        int nl = n0 - 1 + j;                      // node index within graph
        float v = 0.f;
        if (j < count + 2 && nl >= 0 && nl < NLEN)
            v = x[(base + j) * CIN + c];
        xs[f] = v;
    }
    __syncthreads();

    // ---- phase 1: per-node messages + attention logits ----
    const int c0 = tid * 4;                       // this thread's 4 channels
    const int h  = c0 / COUT;
    const float4 bmv = *(const float4*)&bm[c0];
    const float4 atv = *(const float4*)&att[c0];

    float4 acc[TILE + 2];
    #pragma unroll
    for (int i = 0; i < TILE + 2; i++) acc[i] = bmv;

    if constexpr (CIN % 4 == 0) {
        for (int k = 0; k < CIN; k += 4) {
            float4 w0 = *(const float4*)&Wm[(k + 0) * HC + c0];
            float4 w1 = *(const float4*)&Wm[(k + 1) * HC + c0];
            float4 w2 = *(const float4*)&Wm[(k + 2) * HC + c0];
            float4 w3 = *(const float4*)&Wm[(k + 3) * HC + c0];
            #pragma unroll
            for (int i = 0; i < TILE + 2; i++) {
                float4 xv = *(const float4*)&xs[i * CIN + k];   // broadcast read
                acc[i].x = fmaf(xv.x, w0.x, acc[i].x);
                acc[i].y = fmaf(xv.x, w0.y, acc[i].y);
                acc[i].z = fmaf(xv.x, w0.z, acc[i].z);
                acc[i].w = fmaf(xv.x, w0.w, acc[i].w);
                acc[i].x = fmaf(xv.y, w1.x, acc[i].x);
                acc[i].y = fmaf(xv.y, w1.y, acc[i].y);
                acc[i].z = fmaf(xv.y, w1.z, acc[i].z);
                acc[i].w = fmaf(xv.y, w1.w, acc[i].w);
                acc[i].x = fmaf(xv.z, w2.x, acc[i].x);
                acc[i].y = fmaf(xv.z, w2.y, acc[i].y);
                acc[i].z = fmaf(xv.z, w2.z, acc[i].z);
                acc[i].w = fmaf(xv.z, w2.w, acc[i].w);
                acc[i].x = fmaf(xv.w, w3.x, acc[i].x);
                acc[i].y = fmaf(xv.w, w3.y, acc[i].y);
                acc[i].z = fmaf(xv.w, w3.z, acc[i].z);
                acc[i].w = fmaf(xv.w, w3.w, acc[i].w);
            }
        }
    } else {
        for (int k = 0; k < CIN; k++) {
            float4 w0 = *(const float4*)&Wm[k * HC + c0];
            #pragma unroll
            for (int i = 0; i < TILE + 2; i++) {
                float xv = xs[i * CIN + k];
                acc[i].x = fmaf(xv, w0.x, acc[i].x);
                acc[i].y = fmaf(xv, w0.y, acc[i].y);
                acc[i].z = fmaf(xv, w0.z, acc[i].z);
                acc[i].w = fmaf(xv, w0.w, acc[i].w);
            }
        }
    }

    #pragma unroll
    for (int i = 0; i < TILE + 2; i++) {
        float4 m = acc[i];
        m.x = m.x > 0.f ? m.x : 0.01f * m.x;      // leaky_relu(0.01)
        m.y = m.y > 0.f ? m.y : 0.01f * m.y;
        m.z = m.z > 0.f ? m.z : 0.01f * m.z;
        m.w = m.w > 0.f ? m.w : 0.01f * m.w;
        *(float4*)&ms[i * HC + c0] = m;
        float p = m.x * atv.x + m.y * atv.y + m.z * atv.z + m.w * atv.w;
        #pragma unroll
        for (int s = RL >> 1; s > 0; s >>= 1)
            p += __shfl_xor(p, s, 64);            // reduce over the head's lanes
        if ((tid & (RL - 1)) == 0)
            al[i * H + h] = p;
    }
    __syncthreads();

    // ---- phase 2a: softmax weights over incoming edges (<=2) ----
    if (tid < count * H) {
        int i  = tid / H;
        int hh = tid - i * H;
        int nl = n0 + i;
        bool hp = nl > 0;
        bool hn = nl < NLEN - 1;
        float ap = hp ? al[i * H + hh]       : -1e30f;
        float an = hn ? al[(i + 2) * H + hh] : -1e30f;
        float mx = fmaxf(ap, an);
        float ep = hp ? expf(ap - mx) : 0.f;
        float en = hn ? expf(an - mx) : 0.f;
        float inv = 1.f / (ep + en + 1e-16f);
        wp[tid] = ep * inv;
        wn[tid] = en * inv;
    }
    __syncthreads();

    // ---- phase 2b: aggregate + self loop + activation ----
    constexpr int NP = 256 / COUT;                // nodes processed in parallel
    const int co = tid % COUT;
    const int io = tid / COUT;
    for (int i = io; i < count; i += NP) {
        const float* mp  = &ms[i * HC + co];          // prev node row (j = i)
        const float* mn  = &ms[(i + 2) * HC + co];    // next node row (j = i+2)
        const float* wpi = &wp[i * H];
        const float* wni = &wn[i * H];
        float agg = 0.f;
        #pragma unroll
        for (int hh = 0; hh < H; hh++)
            agg += wpi[hh] * mp[hh * COUT] + wni[hh] * mn[hh * COUT];
        float o = agg * (1.0f / H) + bs[co];
        for (int k = 0; k < CIN; k++)
            o = fmaf(xs[(i + 1) * CIN + k], Ws[k * COUT + co], o);
        if constexpr (DO_ELU) o = o > 0.f ? o : expf(o) - 1.f;
        y[(base + 1 + i) * COUT + co] = o;
    }
}

// Layer 5 + head, evaluated only at the last node of each graph.
// Node N-1 has exactly one incoming edge (from N-2) -> softmax weight == 1, att unused.
__global__ void final_head(const float* __restrict__ x4,   // [NUMV][64]
                           const float* __restrict__ Wm,   // [64][32]
                           const float* __restrict__ bm,   // [32]
                           const float* __restrict__ Ws,   // [64][32]
                           const float* __restrict__ bs,   // [32]
                           const float* __restrict__ Wc,   // [32][1]
                           const float* __restrict__ bc,   // [1]
                           float* __restrict__ out)        // [32] ++ [32*32]
{
    int g = blockIdx.x;
    int c = threadIdx.x;                                   // 64 lanes, 32 active
    const float* xu = &x4[((long)g * NLEN + NLEN - 2) * 64];  // node N-2
    const float* xv = xu + 64;                                // node N-1
    float o = 0.f;
    if (c < 32) {
        float m = bm[c];
        float s = bs[c];
        for (int k = 0; k < 64; k++) {
            m = fmaf(xu[k], Wm[k * 32 + c], m);
            s = fmaf(xv[k], Ws[k * 32 + c], s);
        }
        m = m > 0.f ? m : 0.01f * m;                       // leaky_relu on the message
        o = m + s;                                         // H=1: head mean = identity
        out[32 + g * 32 + c] = o;                          // second output, [B,32]
    }
    float tsum = (c < 32) ? o * Wc[c] : 0.f;
    #pragma unroll
    for (int sft = 16; sft > 0; sft >>= 1)
        tsum += __shfl_xor(tsum, sft, 64);
    if (c == 0) out[g] = tsum + bc[0];                     // first output, [B,1]
}

extern "C" void kernel_launch(void* const* d_in, const int* in_sizes, int n_in,
                              void* d_out, int out_size, void* d_ws, size_t ws_size,
                              hipStream_t stream)
{
    constexpr int TILE = 14;
    constexpr int TPG  = (NLEN + TILE - 1) / TILE;

    const float* nodes = (const float*)d_in[0];
    auto L = [&](int l, int k) { return (const float*)d_in[1 + (l - 1) * 5 + k]; };

    float* xb0 = (float*)d_ws;                       // [NUMV][128] fp32
    float* xb1 = xb0 + (size_t)NUMV * 128;           // [NUMV][128] fp32

    dim3 grid(BATCH * TPG);
    dim3 blk(256);

    // layer 1: cin=1, cout=128, H=8
    {
        constexpr size_t sh = ((TILE + 2) * (1 + 1024 + 8) + 2 * TILE * 8) * sizeof(float);
        hipFuncSetAttribute(reinterpret_cast<const void*>(conv_layer<1, 128, 8, TILE, true>),
                            hipFuncAttributeMaxDynamicSharedMemorySize, (int)sh);
        conv_layer<1, 128, 8, TILE, true><<<grid, blk, sh, stream>>>(
            nodes, L(1,0), L(1,1), L(1,2), L(1,3), L(1,4), xb0);
    }
    // layer 2: cin=128, cout=128, H=8
    {
        constexpr size_t sh = ((TILE + 2) * (128 + 1024 + 8) + 2 * TILE * 8) * sizeof(float);
        hipFuncSetAttribute(reinterpret_cast<const void*>(conv_layer<128, 128, 8, TILE, true>),
                            hipFuncAttributeMaxDynamicSharedMemorySize, (int)sh);
        conv_layer<128, 128, 8, TILE, true><<<grid, blk, sh, stream>>>(
            xb0, L(2,0), L(2,1), L(2,2), L(2,3), L(2,4), xb1);
    }
    // layer 3: cin=128, cout=64, H=16
    {
        constexpr size_t sh = ((TILE + 2) * (128 + 1024 + 16) + 2 * TILE * 16) * sizeof(float);
        hipFuncSetAttribute(reinterpret_cast<const void*>(conv_layer<128, 64, 16, TILE, true>),
                            hipFuncAttributeMaxDynamicSharedMemorySize, (int)sh);
        conv_layer<128, 64, 16, TILE, true><<<grid, blk, sh, stream>>>(
            xb1, L(3,0), L(3,1), L(3,2), L(3,3), L(3,4), xb0);
    }
    // layer 4: cin=64, cout=64, H=16
    {
        constexpr size_t sh = ((TILE + 2) * (64 + 1024 + 16) + 2 * TILE * 16) * sizeof(float);
        hipFuncSetAttribute(reinterpret_cast<const void*>(conv_layer<64, 64, 16, TILE, true>),
                            hipFuncAttributeMaxDynamicSharedMemorySize, (int)sh);
        conv_layer<64, 64, 16, TILE, true><<<grid, blk, sh, stream>>>(
            xb0, L(4,0), L(4,1), L(4,2), L(4,3), L(4,4), xb1);
    }
    // layer 5 + classifier head: only the last node per graph matters
    final_head<<<dim3(BATCH), dim3(64), 0, stream>>>(
        xb1, L(5,0), L(5,1), L(5,2), L(5,3),
        (const float*)d_in[26], (const float*)d_in[27], (float*)d_out);
}

// Round 2
// 597.520 us; speedup vs baseline: 1.0327x; 1.0327x over previous
//
#include <hip/hip_runtime.h>

#define BATCH 32
#define NLEN  1024
#define NUMV  (BATCH * NLEN)

typedef __attribute__((ext_vector_type(8))) short short8;
typedef __attribute__((ext_vector_type(4))) float f32x4;

// Split fp32 into bf16 hi + bf16 lo (round-to-nearest both): x ~= hi + lo, rel err ~2^-17.
__device__ __host__ inline void bsplit(float x, unsigned short& h, unsigned short& l) {
    union { float f; unsigned u; } a; a.f = x;
    unsigned hb = (a.u + 0x7FFFu + ((a.u >> 16) & 1u)) & 0xFFFF0000u;
    h = (unsigned short)(hb >> 16);
    union { unsigned u; float f; } hf; hf.u = hb;
    float res = x - hf.f;
    union { float f; unsigned u; } b; b.f = res;
    l = (unsigned short)((b.u + 0x7FFFu + ((b.u >> 16) & 1u)) >> 16);
}

// Pack [Wm | Ws] (fp32) into MFMA-lane-ordered bf16 hi/lo buffers.
// Flat layout: f = ((kc*NT + nt)*16 + c)*32 + g*8 + j  -> value W[k = kc*32+g*8+j][col = nt*16+c]
// (zero-padded for k >= CIN). Same (g,j)->k mapping is used for the A fragments, so the
// kernel is invariant to the true HW K-blocking (K-permutation invariance of matmul).
template<int CIN, int COUT, int H>
__global__ void pack_weights(const float* __restrict__ Wm,
                             const float* __restrict__ Ws,
                             unsigned short* __restrict__ hi,
                             unsigned short* __restrict__ lo)
{
    constexpr int HC = H * COUT;
    constexpr int NCOLS = HC + COUT;
    constexpr int NT = NCOLS / 16;
    constexpr int CINP = (CIN + 31) & ~31;
    constexpr int KC = CINP / 32;
    const int total = KC * NT * 512;
    for (int f = blockIdx.x * 256 + threadIdx.x; f < total; f += gridDim.x * 256) {
        int j  = f & 7;
        int g  = (f >> 3) & 3;
        int c  = (f >> 5) & 15;
        int rest = f >> 9;
        int nt = rest % NT;
        int kc = rest / NT;
        int k   = kc * 32 + g * 8 + j;
        int col = nt * 16 + c;
        float v = 0.f;
        if (k < CIN) v = (col < HC) ? Wm[k * HC + col] : Ws[k * COUT + (col - HC)];
        unsigned short h, l; bsplit(v, h, l);
        hi[f] = h; lo[f] = l;
    }
}

// Fused GeneralConv layer, MFMA phase 1 (messages + self-loop as one GEMM), 16-row tile.
template<int CIN, int COUT, int H, bool DO_ELU>
__global__ __launch_bounds__(256, 2)
void conv_mfma(const float* __restrict__ x,
               const unsigned short* __restrict__ pw_hi,
               const unsigned short* __restrict__ pw_lo,
               const float* __restrict__ bm,
               const float* __restrict__ bs,
               const float* __restrict__ att,   // [H*COUT] flat == att[h][c]
               float* __restrict__ y)
{
    constexpr int HC    = H * COUT;
    constexpr int TILE  = 14;
    constexpr int ROWS  = 16;
    constexpr int CINP  = (CIN + 31) & ~31;
    constexpr int KC    = CINP / 32;
    constexpr int NCOLS = HC + COUT;
    constexpr int NT    = NCOLS / 16;       // total 16-col tiles (msg + self)
    constexpr int MT    = HC / 16;          // message tiles
    constexpr int HTILES = COUT / 16;       // tiles per head
    constexpr int XSW   = CINP + 4;         // padded x row stride (16B aligned, conflict-free)
    constexpr int MSW   = HC + 4;
    constexpr int SSW   = COUT + 4;
    constexpr int TPG   = (NLEN + TILE - 1) / TILE;
    static_assert(HC == 1024, "");

    const int tid  = threadIdx.x;
    const int lane = tid & 63;
    const int wv   = tid >> 6;              // wave 0..3
    const int g    = blockIdx.x / TPG;
    const int t    = blockIdx.x % TPG;
    const int n0   = t * TILE;
    const int count = (NLEN - n0) < TILE ? (NLEN - n0) : TILE;
    const long base = (long)g * NLEN + n0 - 1;   // node at local row 0

    extern __shared__ float lds[];
    float* ms = lds;                         // ROWS*MSW   (post-relu messages, by global col)
    float* xs = lds;                         // ROWS*XSW   -- aliases ms; dead before ms writes
    float* ss = lds + ROWS * MSW;            // ROWS*SSW   (self-loop outputs incl. bias)
    float* al = ss + ROWS * SSW;             // ROWS*H     (attention logits)
    float* wp = al + ROWS * H;               // TILE*H
    float* wn = wp + TILE * H;               // TILE*H

    // ---- stage x tile (+halo, zero-padded) & zero logits ----
    for (int f = tid; f < ROWS * XSW; f += 256) {
        int j = f / XSW, c = f - j * XSW;
        int nl = n0 - 1 + j;
        float v = 0.f;
        if (c < CIN && j < count + 2 && nl >= 0 && nl < NLEN)
            v = x[(base + j) * CIN + c];
        xs[f] = v;
    }
    for (int f = tid; f < ROWS * H; f += 256) al[f] = 0.f;
    __syncthreads();

    // ---- build A fragments (bf16 hi/lo) in registers ----
    const int r  = lane & 15;    // A row / B col / C col
    const int gg = lane >> 4;    // k-group
    short8 a_hi[KC], a_lo[KC];
    #pragma unroll
    for (int kc = 0; kc < KC; kc++) {
        const float* p = &xs[r * XSW + kc * 32 + gg * 8];
        f32x4 v0 = *(const f32x4*)p;
        f32x4 v1 = *(const f32x4*)(p + 4);
        float vals[8] = {v0[0], v0[1], v0[2], v0[3], v1[0], v1[1], v1[2], v1[3]};
        union { short8 v; unsigned short u[8]; } hu, lu;
        #pragma unroll
        for (int j = 0; j < 8; j++) bsplit(vals[j], hu.u[j], lu.u[j]);
        a_hi[kc] = hu.v; a_lo[kc] = lu.v;
    }
    __syncthreads();   // xs dead; ms region reusable

    // ---- phase 1: MFMA over n-tiles (double-buffered B frags) ----
    constexpr int NITER = (NT + 3) / 4;
    short8 nbh[KC], nbl[KC];
    {
        const long wb0 = (long)wv * 512 + r * 32 + gg * 8;
        #pragma unroll
        for (int kc = 0; kc < KC; kc++) {
            nbh[kc] = *(const short8*)&pw_hi[wb0 + (long)kc * NT * 512];
            nbl[kc] = *(const short8*)&pw_lo[wb0 + (long)kc * NT * 512];
        }
    }
    for (int it = 0; it < NITER; it++) {
        const int nt = wv + it * 4;
        if (nt >= NT) break;
        short8 bh[KC], bl[KC];
        #pragma unroll
        for (int kc = 0; kc < KC; kc++) { bh[kc] = nbh[kc]; bl[kc] = nbl[kc]; }
        const int ntn = nt + 4;
        if (ntn < NT) {
            const long wbn = (long)ntn * 512 + r * 32 + gg * 8;
            #pragma unroll
            for (int kc = 0; kc < KC; kc++) {
                nbh[kc] = *(const short8*)&pw_hi[wbn + (long)kc * NT * 512];
                nbl[kc] = *(const short8*)&pw_lo[wbn + (long)kc * NT * 512];
            }
        }
        const bool isMsg = nt < MT;
        const int col = nt * 16 + r;
        const float b = isMsg ? bm[col] : bs[col - HC];
        f32x4 acc = {b, b, b, b};
        #pragma unroll
        for (int kc = 0; kc < KC; kc++) {
            acc = __builtin_amdgcn_mfma_f32_16x16x32_bf16(a_hi[kc], bh[kc], acc, 0, 0, 0);
            acc = __builtin_amdgcn_mfma_f32_16x16x32_bf16(a_hi[kc], bl[kc], acc, 0, 0, 0);
            acc = __builtin_amdgcn_mfma_f32_16x16x32_bf16(a_lo[kc], bh[kc], acc, 0, 0, 0);
        }
        // C/D layout: col = lane&15, row = (lane>>4)*4 + reg  [HW-verified]
        if (isMsg) {
            const float attv = att[col];
            const int hh = nt / HTILES;
            float p[4];
            #pragma unroll
            for (int e = 0; e < 4; e++) {
                float v = acc[e];
                v = v > 0.f ? v : 0.01f * v;            // leaky_relu(0.01)
                ms[(gg * 4 + e) * MSW + col] = v;
                p[e] = v * attv;
            }
            #pragma unroll
            for (int s = 1; s < 16; s <<= 1) {
                #pragma unroll
                for (int e = 0; e < 4; e++) p[e] += __shfl_xor(p[e], s, 64);
            }
            if (r == 0) {
                #pragma unroll
                for (int e = 0; e < 4; e++) atomicAdd(&al[(gg * 4 + e) * H + hh], p[e]);
            }
        } else {
            const int c = col - HC;
            #pragma unroll
            for (int e = 0; e < 4; e++) ss[(gg * 4 + e) * SSW + c] = acc[e];
        }
    }
    __syncthreads();

    // ---- phase 2a: softmax weights over <=2 incoming edges ----
    if (tid < count * H) {
        int i  = tid / H;
        int hh = tid - i * H;
        int nl = n0 + i;
        bool hp = nl > 0;
        bool hn = nl < NLEN - 1;
        float ap = hp ? al[i * H + hh]       : -1e30f;
        float an = hn ? al[(i + 2) * H + hh] : -1e30f;
        float mx = fmaxf(ap, an);
        float ep = hp ? expf(ap - mx) : 0.f;
        float en = hn ? expf(an - mx) : 0.f;
        float inv = 1.f / (ep + en + 1e-16f);
        wp[tid] = ep * inv;
        wn[tid] = en * inv;
    }
    __syncthreads();

    // ---- phase 2b: head-mean aggregate + self + activation ----
    constexpr int NP = 256 / COUT;
    const int co = tid % COUT;
    const int io = tid / COUT;
    for (int i = io; i < count; i += NP) {
        const float* mp  = &ms[i * MSW + co];
        const float* mn  = &ms[(i + 2) * MSW + co];
        const float* wpi = &wp[i * H];
        const float* wni = &wn[i * H];
        float agg = 0.f;
        #pragma unroll
        for (int hh = 0; hh < H; hh++)
            agg += wpi[hh] * mp[hh * COUT] + wni[hh] * mn[hh * COUT];
        float o = agg * (1.0f / H) + ss[(i + 1) * SSW + co];
        if constexpr (DO_ELU) o = o > 0.f ? o : expf(o) - 1.f;
        y[(base + 1 + i) * COUT + co] = o;
    }
}

// Layer 5 + head at the last node of each graph (single incoming edge -> softmax weight 1).
__global__ void final_head(const float* __restrict__ x4,   // [NUMV][64]
                           const float* __restrict__ Wm,   // [64][32]
                           const float* __restrict__ bm,
                           const float* __restrict__ Ws,   // [64][32]
                           const float* __restrict__ bs,
                           const float* __restrict__ Wc,   // [32][1]
                           const float* __restrict__ bc,
                           float* __restrict__ out)        // [32] ++ [32*32]
{
    int g = blockIdx.x;
    int c = threadIdx.x;
    const float* xu = &x4[((long)g * NLEN + NLEN - 2) * 64];
    const float* xv = xu + 64;
    float o = 0.f;
    if (c < 32) {
        float m = bm[c];
        float s = bs[c];
        for (int k = 0; k < 64; k++) {
            m = fmaf(xu[k], Wm[k * 32 + c], m);
            s = fmaf(xv[k], Ws[k * 32 + c], s);
        }
        m = m > 0.f ? m : 0.01f * m;
        o = m + s;
        out[32 + g * 32 + c] = o;
    }
    float tsum = (c < 32) ? o * Wc[c] : 0.f;
    #pragma unroll
    for (int sft = 16; sft > 0; sft >>= 1)
        tsum += __shfl_xor(tsum, sft, 64);
    if (c == 0) out[g] = tsum + bc[0];
}

extern "C" void kernel_launch(void* const* d_in, const int* in_sizes, int n_in,
                              void* d_out, int out_size, void* d_ws, size_t ws_size,
                              hipStream_t stream)
{
    constexpr int TILE = 14;
    constexpr int TPG  = (NLEN + TILE - 1) / TILE;

    const float* nodes = (const float*)d_in[0];
    auto L = [&](int l, int k) { return (const float*)d_in[1 + (l - 1) * 5 + k]; };

    float* xb0 = (float*)d_ws;                       // [NUMV][128]
    float* xb1 = xb0 + (size_t)NUMV * 128;
    unsigned short* pk = (unsigned short*)(xb1 + (size_t)NUMV * 128);

    // packed sizes (ushorts): L1: 1*72*512, L2: 4*72*512, L3: 4*68*512, L4: 2*68*512
    constexpr int S1 = 1 * 72 * 512, S2 = 4 * 72 * 512, S3 = 4 * 68 * 512, S4 = 2 * 68 * 512;
    unsigned short* h1 = pk;            unsigned short* l1 = h1 + S1;
    unsigned short* h2 = l1 + S1;       unsigned short* l2 = h2 + S2;
    unsigned short* h3 = l2 + S2;       unsigned short* l3 = h3 + S3;
    unsigned short* h4 = l3 + S3;       unsigned short* l4 = h4 + S4;

    pack_weights<1, 128, 8><<<dim3(64), dim3(256), 0, stream>>>(L(1,0), L(1,2), h1, l1);
    pack_weights<128, 128, 8><<<dim3(256), dim3(256), 0, stream>>>(L(2,0), L(2,2), h2, l2);
    pack_weights<128, 64, 16><<<dim3(256), dim3(256), 0, stream>>>(L(3,0), L(3,2), h3, l3);
    pack_weights<64, 64, 16><<<dim3(128), dim3(256), 0, stream>>>(L(4,0), L(4,2), h4, l4);

    dim3 grid(BATCH * TPG);
    dim3 blk(256);

    // dynamic LDS bytes: (16*(HC+4) + 16*(COUT+4) + 16*H + 2*TILE*H) * 4
    auto launch = [&](auto kern, size_t sh, const float* xin,
                      const unsigned short* hi, const unsigned short* lo,
                      int l, float* yout) {
        hipFuncSetAttribute(reinterpret_cast<const void*>(kern),
                            hipFuncAttributeMaxDynamicSharedMemorySize, (int)sh);
        kern<<<grid, blk, sh, stream>>>(xin, hi, lo, L(l,1), L(l,3), L(l,4), yout);
    };

    constexpr size_t shA = (16 * 1028 + 16 * 132 + 16 * 8 + 2 * TILE * 8) * 4;   // H=8,COUT=128
    constexpr size_t shB = (16 * 1028 + 16 * 68  + 16 * 16 + 2 * TILE * 16) * 4; // H=16,COUT=64

    launch(conv_mfma<1, 128, 8, true>,   shA, nodes, h1, l1, 1, xb0);
    launch(conv_mfma<128, 128, 8, true>, shA, xb0,   h2, l2, 2, xb1);
    launch(conv_mfma<128, 64, 16, true>, shB, xb1,   h3, l3, 3, xb0);
    launch(conv_mfma<64, 64, 16, true>,  shB, xb0,   h4, l4, 4, xb1);

    final_head<<<dim3(BATCH), dim3(64), 0, stream>>>(
        xb1, L(5,0), L(5,1), L(5,2), L(5,3),
        (const float*)d_in[26], (const float*)d_in[27], (float*)d_out);
}

// Round 3
// 401.319 us; speedup vs baseline: 1.5376x; 1.4889x over previous
//
#include <hip/hip_runtime.h>

#define BATCH 32
#define NLEN  1024
#define NUMV  (BATCH * NLEN)

typedef __attribute__((ext_vector_type(8))) short short8;
typedef __attribute__((ext_vector_type(4))) float f32x4;

__device__ inline unsigned short rne_bf16(float x) {
    union { float f; unsigned u; } a; a.f = x;
    return (unsigned short)((a.u + 0x7FFFu + ((a.u >> 16) & 1u)) >> 16);
}
// fp32 -> bf16 hi + bf16 lo (both RNE): x ~= hi + lo, rel err ~2^-17
__device__ inline void bsplit(float x, unsigned short& h, unsigned short& l) {
    union { float f; unsigned u; } a; a.f = x;
    unsigned hb = (a.u + 0x7FFFu + ((a.u >> 16) & 1u)) & 0xFFFF0000u;
    h = (unsigned short)(hb >> 16);
    union { unsigned u; float f; } hf; hf.u = hb;
    l = rne_bf16(x - hf.f);
}
__device__ inline float bf16_to_f(unsigned short v) {
    union { unsigned u; float f; } a; a.u = ((unsigned)v) << 16; return a.f;
}

// Packed layout per layer: f = ((nt*KC + kc)*2 + hl)*512 + c*32 + g*8 + j
//   -> W[k = kc*32+g*8+j][col = nt*16+c], W = [Wm | Ws], zero-pad k >= CIN.
// hl: 0 = hi bf16, 1 = lo bf16. One B tile (all kc, hi+lo) is contiguous: KC*2KB.
template<int CIN, int COUT, int H>
__device__ void pack_layer(const float* __restrict__ Wm, const float* __restrict__ Ws,
                           unsigned short* __restrict__ out, int t0, int nthr)
{
    constexpr int HC = H * COUT;
    constexpr int KC = ((CIN + 31) & ~31) / 32;
    constexpr int NT = (HC + COUT) / 16;
    const int total = NT * KC * 1024;
    for (int f = t0; f < total; f += nthr) {
        int j = f & 7, g = (f >> 3) & 3, c = (f >> 5) & 15, hl = (f >> 9) & 1;
        int r2 = f >> 10;
        int kc = r2 % KC, nt = r2 / KC;
        int k = kc * 32 + g * 8 + j, col = nt * 16 + c;
        float v = 0.f;
        if (k < CIN) v = (col < HC) ? Wm[k * HC + col] : Ws[k * COUT + (col - HC)];
        unsigned short h, l; bsplit(v, h, l);
        out[f] = hl ? l : h;
    }
}

__global__ void pack_all(const float* Wm1, const float* Ws1, const float* Wm2, const float* Ws2,
                         const float* Wm3, const float* Ws3, const float* Wm4, const float* Ws4,
                         unsigned short* p1, unsigned short* p2, unsigned short* p3, unsigned short* p4)
{
    int t = blockIdx.x * 256 + threadIdx.x;
    int n = gridDim.x * 256;
    pack_layer<1, 128, 8>(Wm1, Ws1, p1, t, n);
    pack_layer<128, 128, 8>(Wm2, Ws2, p2, t, n);
    pack_layer<128, 64, 16>(Wm3, Ws3, p3, t, n);
    pack_layer<64, 64, 16>(Wm4, Ws4, p4, t, n);
}

// Register-resident fused GeneralConv layer.
// Block = 4 waves; wave owns 2 row-sets of 16 (14 useful + halo); block = 112 useful rows.
// Per head: messages live in VGPRs; logits in-register (one butterfly/head);
// softmax + neighbor aggregation via lane shuffles. B double-buffered in LDS (16 KB).
template<int CIN, int COUT, int H, bool MPACK>
__global__ __launch_bounds__(256, 2)
void conv_reg(const float* __restrict__ x, const unsigned short* __restrict__ pw,
              const float* __restrict__ bm, const float* __restrict__ bs,
              const float* __restrict__ att, float* __restrict__ y)
{
    constexpr int HC = H * COUT;
    static_assert(HC == 1024, "");
    constexpr int KC   = ((CIN + 31) & ~31) / 32;
    constexpr int HT   = COUT / 16;          // tiles per head == self tiles
    constexpr int MT   = HC / 16;            // 64 message tiles
    constexpr int NTOT = MT + HT;
    constexpr int NCH  = KC * 128;           // 16B chunks per B tile (KC*2KB)
    constexpr int CHPT = (NCH + 255) / 256;  // chunks per thread
    constexpr int ROWSB = 112;
    constexpr int TPG  = (NLEN + ROWSB - 1) / ROWSB;  // 10
    constexpr float invH = 1.0f / H;

    const int tid  = threadIdx.x;
    const int lane = tid & 63;
    const int w    = tid >> 6;
    const int r    = lane & 15;               // A row in set / B col / C col
    const int gg   = lane >> 4;               // k-group; C row = gg*4+e
    const int g    = blockIdx.x / TPG;
    const int n0   = (blockIdx.x % TPG) * ROWSB;
    const size_t gstart = (size_t)g * NLEN;

    __shared__ alignas(16) unsigned short bufs[2][KC * 1024];

    // ---- A fragments (built once, from global) ----
    short8 a_hi[2][KC], a_lo[2][KC];
    #pragma unroll
    for (int s = 0; s < 2; s++) {
        const int na = n0 - 1 + w * 28 + s * 14 + r;     // within-graph node idx of A row
        const bool av = (na >= 0) && (na < NLEN);
        const float* xrow = x + (gstart + (size_t)(av ? na : 0)) * CIN;
        #pragma unroll
        for (int kc = 0; kc < KC; kc++) {
            float vals[8];
            if constexpr (CIN % 32 == 0) {
                if (av) {
                    f32x4 v0 = *(const f32x4*)(xrow + kc * 32 + gg * 8);
                    f32x4 v1 = *(const f32x4*)(xrow + kc * 32 + gg * 8 + 4);
                    vals[0]=v0[0]; vals[1]=v0[1]; vals[2]=v0[2]; vals[3]=v0[3];
                    vals[4]=v1[0]; vals[5]=v1[1]; vals[6]=v1[2]; vals[7]=v1[3];
                } else {
                    #pragma unroll
                    for (int jj = 0; jj < 8; jj++) vals[jj] = 0.f;
                }
            } else {
                #pragma unroll
                for (int jj = 0; jj < 8; jj++) {
                    int k = kc * 32 + gg * 8 + jj;
                    vals[jj] = (av && k < CIN) ? xrow[k] : 0.f;
                }
            }
            union { short8 v; unsigned short u[8]; } hu, lu;
            #pragma unroll
            for (int jj = 0; jj < 8; jj++) bsplit(vals[jj], hu.u[jj], lu.u[jj]);
            a_hi[s][kc] = hu.v; a_lo[s][kc] = lu.v;
        }
    }

    float out[2][HT][4];
    #pragma unroll
    for (int s = 0; s < 2; s++)
        #pragma unroll
        for (int q = 0; q < HT; q++)
            #pragma unroll
            for (int e = 0; e < 4; e++) out[s][q][e] = 0.f;

    float    mf[2][MPACK ? 1 : HT][4];      // per-head messages, f32 variant
    unsigned mpk[2][MPACK ? HT : 1][2];     // per-head messages, bf16x2 variant

    // ---- prologue: stage B tile 0 ----
    {
        const f32x4* ps = (const f32x4*)pw;
        f32x4 sreg[CHPT];
        #pragma unroll
        for (int i = 0; i < CHPT; i++) { int idx = tid + i * 256; if (idx < NCH) sreg[i] = ps[idx]; }
        #pragma unroll
        for (int i = 0; i < CHPT; i++) { int idx = tid + i * 256; if (idx < NCH) *(f32x4*)&bufs[0][idx * 8] = sreg[i]; }
    }
    __syncthreads();

    // ---- heads ----
    for (int h = 0; h < H; h++) {
        float p[2][4] = {{0.f,0.f,0.f,0.f},{0.f,0.f,0.f,0.f}};
        #pragma unroll
        for (int q = 0; q < HT; q++) {
            const int nt  = h * HT + q;
            const int cur = nt & 1;
            const int ntn = nt + 1;
            const bool doStage = (ntn < NTOT);
            f32x4 sreg[CHPT];
            if (doStage) {                              // issue loads early (hide under MFMA)
                const f32x4* ps = (const f32x4*)pw + (size_t)ntn * NCH;
                #pragma unroll
                for (int i = 0; i < CHPT; i++) { int idx = tid + i * 256; if (idx < NCH) sreg[i] = ps[idx]; }
            }
            const int boff = r * 32 + gg * 8;
            const int col  = nt * 16 + r;
            const float bmv  = bm[col];
            const float attv = att[col];
            short8 bh[KC], bl[KC];
            #pragma unroll
            for (int kc = 0; kc < KC; kc++) {
                bh[kc] = *(const short8*)&bufs[cur][(kc * 2 + 0) * 512 + boff];
                bl[kc] = *(const short8*)&bufs[cur][(kc * 2 + 1) * 512 + boff];
            }
            #pragma unroll
            for (int s = 0; s < 2; s++) {
                f32x4 acc = {bmv, bmv, bmv, bmv};
                #pragma unroll
                for (int kc = 0; kc < KC; kc++) {
                    acc = __builtin_amdgcn_mfma_f32_16x16x32_bf16(a_hi[s][kc], bh[kc], acc, 0, 0, 0);
                    acc = __builtin_amdgcn_mfma_f32_16x16x32_bf16(a_hi[s][kc], bl[kc], acc, 0, 0, 0);
                    acc = __builtin_amdgcn_mfma_f32_16x16x32_bf16(a_lo[s][kc], bh[kc], acc, 0, 0, 0);
                }
                float vv[4];
                #pragma unroll
                for (int e = 0; e < 4; e++) {
                    float v = acc[e];
                    v = v > 0.f ? v : 0.01f * v;        // leaky_relu(0.01)
                    vv[e] = v;
                    p[s][e] += v * attv;                // logit partial (col r only)
                }
                if constexpr (MPACK) {
                    mpk[s][q][0] = ((unsigned)rne_bf16(vv[1]) << 16) | rne_bf16(vv[0]);
                    mpk[s][q][1] = ((unsigned)rne_bf16(vv[3]) << 16) | rne_bf16(vv[2]);
                } else {
                    #pragma unroll
                    for (int e = 0; e < 4; e++) mf[s][q][e] = vv[e];
                }
            }
            if (doStage) {                              // write-late (after loads landed)
                const int nb = ntn & 1;
                #pragma unroll
                for (int i = 0; i < CHPT; i++) { int idx = tid + i * 256; if (idx < NCH) *(f32x4*)&bufs[nb][idx * 8] = sreg[i]; }
            }
            __syncthreads();
        }
        // ---- logits: butterfly all-reduce over the 16 lanes of each row ----
        #pragma unroll
        for (int s = 0; s < 2; s++)
            #pragma unroll
            for (int e = 0; e < 4; e++) {
                float v = p[s][e];
                v += __shfl_xor(v, 1, 64);
                v += __shfl_xor(v, 2, 64);
                v += __shfl_xor(v, 4, 64);
                v += __shfl_xor(v, 8, 64);
                p[s][e] = v;                            // alpha[row gg*4+e]
            }
        // ---- softmax over <=2 incoming edges + aggregate into out regs ----
        #pragma unroll
        for (int s = 0; s < 2; s++) {
            const int jbase = w * 28 + s * 14;
            float a3u = __shfl_up(p[s][3], 16, 64);     // alpha of row-1 for e==0
            float a0d = __shfl_down(p[s][0], 16, 64);   // alpha of row+1 for e==3
            float wpv[4], wnv[4];
            #pragma unroll
            for (int e = 0; e < 4; e++) {
                const int jr = gg * 4 + e;
                const int nl = n0 - 1 + jbase + jr;     // within-graph node idx
                const bool hp = nl >= 1;
                const bool hn = nl < NLEN - 1;
                float ap = (e > 0) ? p[s][e - 1] : a3u;
                float an = (e < 3) ? p[s][e + 1] : a0d;
                float apx = hp ? ap : -1e30f;
                float anx = hn ? an : -1e30f;
                float mx = fmaxf(apx, anx);
                float ep = hp ? __expf(ap - mx) : 0.f;
                float en = hn ? __expf(an - mx) : 0.f;
                float inv = 1.f / (ep + en + 1e-16f);
                wpv[e] = ep * inv; wnv[e] = en * inv;
            }
            #pragma unroll
            for (int q = 0; q < HT; q++) {
                float v0, v1, v2, v3;
                if constexpr (MPACK) {
                    v0 = bf16_to_f((unsigned short)(mpk[s][q][0] & 0xffff));
                    v1 = bf16_to_f((unsigned short)(mpk[s][q][0] >> 16));
                    v2 = bf16_to_f((unsigned short)(mpk[s][q][1] & 0xffff));
                    v3 = bf16_to_f((unsigned short)(mpk[s][q][1] >> 16));
                } else {
                    v0 = mf[s][q][0]; v1 = mf[s][q][1]; v2 = mf[s][q][2]; v3 = mf[s][q][3];
                }
                float m3u = __shfl_up(v3, 16, 64);      // M[row-1] for e==0
                float m0d = __shfl_down(v0, 16, 64);    // M[row+1] for e==3
                float mvals[4] = {v0, v1, v2, v3};
                #pragma unroll
                for (int e = 0; e < 4; e++) {
                    float mprev = (e > 0) ? mvals[e - 1] : m3u;
                    float mnext = (e < 3) ? mvals[e + 1] : m0d;
                    out[s][q][e] += wpv[e] * mprev + wnv[e] * mnext;
                }
            }
        }
    }

    // ---- self-loop tiles + finalize + store ----
    #pragma unroll
    for (int q2 = 0; q2 < HT; q2++) {
        const int nt  = MT + q2;
        const int cur = nt & 1;
        const int ntn = nt + 1;
        const bool doStage = (ntn < NTOT);
        f32x4 sreg[CHPT];
        if (doStage) {
            const f32x4* ps = (const f32x4*)pw + (size_t)ntn * NCH;
            #pragma unroll
            for (int i = 0; i < CHPT; i++) { int idx = tid + i * 256; if (idx < NCH) sreg[i] = ps[idx]; }
        }
        const int boff = r * 32 + gg * 8;
        const int c2   = q2 * 16 + r;
        const float bsv = bs[c2];
        short8 bh[KC], bl[KC];
        #pragma unroll
        for (int kc = 0; kc < KC; kc++) {
            bh[kc] = *(const short8*)&bufs[cur][(kc * 2 + 0) * 512 + boff];
            bl[kc] = *(const short8*)&bufs[cur][(kc * 2 + 1) * 512 + boff];
        }
        #pragma unroll
        for (int s = 0; s < 2; s++) {
            f32x4 acc = {bsv, bsv, bsv, bsv};
            #pragma unroll
            for (int kc = 0; kc < KC; kc++) {
                acc = __builtin_amdgcn_mfma_f32_16x16x32_bf16(a_hi[s][kc], bh[kc], acc, 0, 0, 0);
                acc = __builtin_amdgcn_mfma_f32_16x16x32_bf16(a_hi[s][kc], bl[kc], acc, 0, 0, 0);
                acc = __builtin_amdgcn_mfma_f32_16x16x32_bf16(a_lo[s][kc], bh[kc], acc, 0, 0, 0);
            }
            const int jbase = w * 28 + s * 14;
            #pragma unroll
            for (int e = 0; e < 4; e++) {
                const int jr = gg * 4 + e;
                const int nl = n0 - 1 + jbase + jr;
                float v = out[s][q2][e] * invH + acc[e];
                v = v > 0.f ? v : __expf(v) - 1.f;      // ELU (layers 1..4)
                if (jr >= 1 && jr <= 14 && nl < NLEN)
                    y[(gstart + nl) * COUT + c2] = v;
            }
        }
        if (doStage) {
            const int nb = ntn & 1;
            #pragma unroll
            for (int i = 0; i < CHPT; i++) { int idx = tid + i * 256; if (idx < NCH) *(f32x4*)&bufs[nb][idx * 8] = sreg[i]; }
        }
        __syncthreads();
    }
}

// Layer 5 + head at the last node per graph (single incoming edge -> softmax weight 1).
__global__ void final_head(const float* __restrict__ x4,   // [NUMV][64]
                           const float* __restrict__ Wm,   // [64][32]
                           const float* __restrict__ bm,
                           const float* __restrict__ Ws,   // [64][32]
                           const float* __restrict__ bs,
                           const float* __restrict__ Wc,   // [32][1]
                           const float* __restrict__ bc,
                           float* __restrict__ out)        // [32] ++ [32*32]
{
    int g = blockIdx.x;
    int c = threadIdx.x;
    const float* xu = &x4[((long)g * NLEN + NLEN - 2) * 64];
    const float* xv = xu + 64;
    float o = 0.f;
    if (c < 32) {
        float m = bm[c];
        float s = bs[c];
        for (int k = 0; k < 64; k++) {
            m = fmaf(xu[k], Wm[k * 32 + c], m);
            s = fmaf(xv[k], Ws[k * 32 + c], s);
        }
        m = m > 0.f ? m : 0.01f * m;
        o = m + s;
        out[32 + g * 32 + c] = o;
    }
    float tsum = (c < 32) ? o * Wc[c] : 0.f;
    #pragma unroll
    for (int sft = 16; sft > 0; sft >>= 1)
        tsum += __shfl_xor(tsum, sft, 64);
    if (c == 0) out[g] = tsum + bc[0];
}

extern "C" void kernel_launch(void* const* d_in, const int* in_sizes, int n_in,
                              void* d_out, int out_size, void* d_ws, size_t ws_size,
                              hipStream_t stream)
{
    const float* nodes = (const float*)d_in[0];
    auto L = [&](int l, int k) { return (const float*)d_in[1 + (l - 1) * 5 + k]; };

    float* xb0 = (float*)d_ws;                       // [NUMV][128] f32
    float* xb1 = xb0 + (size_t)NUMV * 128;
    unsigned short* p1 = (unsigned short*)(xb1 + (size_t)NUMV * 128);
    unsigned short* p2 = p1 + 72 * 1024;             // L1: NT=72, KC=1
    unsigned short* p3 = p2 + 72 * 4096;             // L2: NT=72, KC=4
    unsigned short* p4 = p3 + 68 * 4096;             // L3: NT=68, KC=4
                                                     // L4: NT=68, KC=2

    pack_all<<<dim3(512), dim3(256), 0, stream>>>(
        L(1,0), L(1,2), L(2,0), L(2,2), L(3,0), L(3,2), L(4,0), L(4,2), p1, p2, p3, p4);

    constexpr int TPG = (NLEN + 111) / 112;          // 10
    dim3 grid(BATCH * TPG);
    dim3 blk(256);

    conv_reg<1,   128, 8,  false><<<grid, blk, 0, stream>>>(nodes, p1, L(1,1), L(1,3), L(1,4), xb0);
    conv_reg<128, 128, 8,  true ><<<grid, blk, 0, stream>>>(xb0,   p2, L(2,1), L(2,3), L(2,4), xb1);
    conv_reg<128, 64,  16, false><<<grid, blk, 0, stream>>>(xb1,   p3, L(3,1), L(3,3), L(3,4), xb0);
    conv_reg<64,  64,  16, false><<<grid, blk, 0, stream>>>(xb0,   p4, L(4,1), L(4,3), L(4,4), xb1);

    final_head<<<dim3(BATCH), dim3(64), 0, stream>>>(
        xb1, L(5,0), L(5,1), L(5,2), L(5,3),
        (const float*)d_in[26], (const float*)d_in[27], (float*)d_out);
}

// Round 4
// 341.698 us; speedup vs baseline: 1.8059x; 1.1745x over previous
//
#include <hip/hip_runtime.h>

#define BATCH 32
#define NLEN  1024
#define NUMV  (BATCH * NLEN)

typedef __attribute__((ext_vector_type(8))) short short8;
typedef __attribute__((ext_vector_type(4))) float f32x4;

__device__ inline unsigned short rne_bf16(float x) {
    union { float f; unsigned u; } a; a.f = x;
    return (unsigned short)((a.u + 0x7FFFu + ((a.u >> 16) & 1u)) >> 16);
}
// fp32 -> bf16 hi + bf16 lo (both RNE): x ~= hi + lo, rel err ~2^-17
__device__ inline void bsplit(float x, unsigned short& h, unsigned short& l) {
    union { float f; unsigned u; } a; a.f = x;
    unsigned hb = (a.u + 0x7FFFu + ((a.u >> 16) & 1u)) & 0xFFFF0000u;
    h = (unsigned short)(hb >> 16);
    union { unsigned u; float f; } hf; hf.u = hb;
    l = rne_bf16(x - hf.f);
}
__device__ inline float bf16_to_f(unsigned short v) {
    union { unsigned u; float f; } a; a.u = ((unsigned)v) << 16; return a.f;
}

// Packed layout per layer (bank-conflict-free transposed chunks):
//   f = ((nt*KC + kc)*2 + hl)*512 + g*128 + c*8 + j
//   -> W[k = kc*32+g*8+j][col = nt*16+c], W = [Wm | Ws], zero-pad k >= CIN.
// hl: 0 = hi bf16, 1 = lo bf16. One B tile (all kc, hi+lo) contiguous: KC*2KB.
// Lane (r,gg) reads 16B chunk (gg*16 + r) -> LDS 16B-slot = r mod 8: each
// quarter-wave covers all 8 slots twice (2-way, free).
template<int CIN, int COUT, int H>
__device__ void pack_layer(const float* __restrict__ Wm, const float* __restrict__ Ws,
                           unsigned short* __restrict__ out, int t0, int nthr)
{
    constexpr int HC = H * COUT;
    constexpr int KC = ((CIN + 31) & ~31) / 32;
    constexpr int NT = (HC + COUT) / 16;
    const int total = NT * KC * 1024;
    for (int f = t0; f < total; f += nthr) {
        int j  = f & 7;
        int c  = (f >> 3) & 15;
        int g  = (f >> 7) & 3;
        int hl = (f >> 9) & 1;
        int r2 = f >> 10;
        int kc = r2 % KC, nt = r2 / KC;
        int k = kc * 32 + g * 8 + j, col = nt * 16 + c;
        float v = 0.f;
        if (k < CIN) v = (col < HC) ? Wm[k * HC + col] : Ws[k * COUT + (col - HC)];
        unsigned short h, l; bsplit(v, h, l);
        out[f] = hl ? l : h;
    }
}

__global__ void pack_all(const float* Wm1, const float* Ws1, const float* Wm2, const float* Ws2,
                         const float* Wm3, const float* Ws3, const float* Wm4, const float* Ws4,
                         unsigned short* p1, unsigned short* p2, unsigned short* p3, unsigned short* p4)
{
    int t = blockIdx.x * 256 + threadIdx.x;
    int n = gridDim.x * 256;
    pack_layer<1, 128, 8>(Wm1, Ws1, p1, t, n);
    pack_layer<128, 128, 8>(Wm2, Ws2, p2, t, n);
    pack_layer<128, 64, 16>(Wm3, Ws3, p3, t, n);
    pack_layer<64, 64, 16>(Wm4, Ws4, p4, t, n);
}

// Register-resident fused GeneralConv layer.
// Block = 4 waves; each wave owns ONE 16-row set (14 useful + 2 halo); block = 56 useful rows.
// Grid = 32 graphs * 19 tiles = 608 blocks (occupancy lever vs round 3's 320).
// Per head: messages in VGPRs; logits in-register (one butterfly/head);
// softmax + neighbor aggregation via +-16 lane shuffles. B double-buffered in LDS.
template<int CIN, int COUT, int H, bool MPACK>
__global__ __launch_bounds__(256, 3)
void conv_reg(const float* __restrict__ x, const unsigned short* __restrict__ pw,
              const float* __restrict__ bm, const float* __restrict__ bs,
              const float* __restrict__ att, float* __restrict__ y)
{
    constexpr int HC = H * COUT;
    static_assert(HC == 1024, "");
    constexpr int KC   = ((CIN + 31) & ~31) / 32;
    constexpr int HT   = COUT / 16;          // tiles per head == self tiles
    constexpr int MT   = HC / 16;            // 64 message tiles
    constexpr int NTOT = MT + HT;
    constexpr int NCH  = KC * 128;           // 16B chunks per B tile
    constexpr int CHPT = (NCH + 255) / 256;  // chunks per thread
    constexpr int ROWSB = 56;
    constexpr int TPG  = (NLEN + ROWSB - 1) / ROWSB;  // 19
    constexpr float invH = 1.0f / H;

    const int tid  = threadIdx.x;
    const int lane = tid & 63;
    const int w    = tid >> 6;
    const int r    = lane & 15;               // A row in set / B col / C col
    const int gg   = lane >> 4;               // k-group; C row = gg*4+e
    const int g    = blockIdx.x / TPG;
    const int n0   = (blockIdx.x % TPG) * ROWSB;
    const size_t gstart = (size_t)g * NLEN;

    __shared__ alignas(16) unsigned short bufs[2][KC * 1024];

    // ---- A fragments (one row-set, built once from global) ----
    short8 a_hi[KC], a_lo[KC];
    {
        const int na = n0 - 1 + w * 14 + r;          // within-graph node of A row
        const bool av = (na >= 0) && (na < NLEN);
        const float* xrow = x + (gstart + (size_t)(av ? na : 0)) * CIN;
        #pragma unroll
        for (int kc = 0; kc < KC; kc++) {
            float vals[8];
            if constexpr (CIN % 32 == 0) {
                if (av) {
                    f32x4 v0 = *(const f32x4*)(xrow + kc * 32 + gg * 8);
                    f32x4 v1 = *(const f32x4*)(xrow + kc * 32 + gg * 8 + 4);
                    vals[0]=v0[0]; vals[1]=v0[1]; vals[2]=v0[2]; vals[3]=v0[3];
                    vals[4]=v1[0]; vals[5]=v1[1]; vals[6]=v1[2]; vals[7]=v1[3];
                } else {
                    #pragma unroll
                    for (int jj = 0; jj < 8; jj++) vals[jj] = 0.f;
                }
            } else {
                #pragma unroll
                for (int jj = 0; jj < 8; jj++) {
                    int k = kc * 32 + gg * 8 + jj;
                    vals[jj] = (av && k < CIN) ? xrow[k] : 0.f;
                }
            }
            union { short8 v; unsigned short u[8]; } hu, lu;
            #pragma unroll
            for (int jj = 0; jj < 8; jj++) bsplit(vals[jj], hu.u[jj], lu.u[jj]);
            a_hi[kc] = hu.v; a_lo[kc] = lu.v;
        }
    }

    float out[HT][4];
    #pragma unroll
    for (int q = 0; q < HT; q++)
        #pragma unroll
        for (int e = 0; e < 4; e++) out[q][e] = 0.f;

    float    mf[MPACK ? 1 : HT][4];      // per-head messages, f32 variant
    unsigned mpk[MPACK ? HT : 1][2];     // per-head messages, bf16x2 variant

    // ---- prologue: stage B tile 0 ----
    {
        const f32x4* ps = (const f32x4*)pw;
        f32x4 sreg[CHPT];
        #pragma unroll
        for (int i = 0; i < CHPT; i++) { int idx = tid + i * 256; if (idx < NCH) sreg[i] = ps[idx]; }
        #pragma unroll
        for (int i = 0; i < CHPT; i++) { int idx = tid + i * 256; if (idx < NCH) *(f32x4*)&bufs[0][idx * 8] = sreg[i]; }
    }
    __syncthreads();

    const int boff = gg * 128 + r * 8;       // transposed-chunk read offset (conflict-free)

    // ---- heads ----
    for (int h = 0; h < H; h++) {
        float p[4] = {0.f, 0.f, 0.f, 0.f};
        #pragma unroll
        for (int q = 0; q < HT; q++) {
            const int nt  = h * HT + q;
            const int cur = nt & 1;
            const int ntn = nt + 1;
            const bool doStage = (ntn < NTOT);
            f32x4 sreg[CHPT];
            if (doStage) {                              // issue loads early (hide under MFMA)
                const f32x4* ps = (const f32x4*)pw + (size_t)ntn * NCH;
                #pragma unroll
                for (int i = 0; i < CHPT; i++) { int idx = tid + i * 256; if (idx < NCH) sreg[i] = ps[idx]; }
            }
            const int col  = nt * 16 + r;
            const float bmv  = bm[col];
            const float attv = att[col];
            short8 bh[KC], bl[KC];
            #pragma unroll
            for (int kc = 0; kc < KC; kc++) {
                bh[kc] = *(const short8*)&bufs[cur][(kc * 2 + 0) * 512 + boff];
                bl[kc] = *(const short8*)&bufs[cur][(kc * 2 + 1) * 512 + boff];
            }
            f32x4 acc = {bmv, bmv, bmv, bmv};
            #pragma unroll
            for (int kc = 0; kc < KC; kc++) {
                acc = __builtin_amdgcn_mfma_f32_16x16x32_bf16(a_hi[kc], bh[kc], acc, 0, 0, 0);
                acc = __builtin_amdgcn_mfma_f32_16x16x32_bf16(a_hi[kc], bl[kc], acc, 0, 0, 0);
                acc = __builtin_amdgcn_mfma_f32_16x16x32_bf16(a_lo[kc], bh[kc], acc, 0, 0, 0);
            }
            float vv[4];
            #pragma unroll
            for (int e = 0; e < 4; e++) {
                float v = acc[e];
                v = v > 0.f ? v : 0.01f * v;        // leaky_relu(0.01)
                vv[e] = v;
                p[e] += v * attv;                   // logit partial (col r)
            }
            if constexpr (MPACK) {
                mpk[q][0] = ((unsigned)rne_bf16(vv[1]) << 16) | rne_bf16(vv[0]);
                mpk[q][1] = ((unsigned)rne_bf16(vv[3]) << 16) | rne_bf16(vv[2]);
            } else {
                #pragma unroll
                for (int e = 0; e < 4; e++) mf[q][e] = vv[e];
            }
            if (doStage) {                              // write-late (loads have landed)
                const int nb = ntn & 1;
                #pragma unroll
                for (int i = 0; i < CHPT; i++) { int idx = tid + i * 256; if (idx < NCH) *(f32x4*)&bufs[nb][idx * 8] = sreg[i]; }
            }
            __syncthreads();
        }
        // ---- logits: butterfly all-reduce over the 16 lanes of each row ----
        #pragma unroll
        for (int e = 0; e < 4; e++) {
            float v = p[e];
            v += __shfl_xor(v, 1, 64);
            v += __shfl_xor(v, 2, 64);
            v += __shfl_xor(v, 4, 64);
            v += __shfl_xor(v, 8, 64);
            p[e] = v;                                   // alpha[row gg*4+e]
        }
        // ---- softmax over <=2 incoming edges + aggregate into out regs ----
        {
            const int jbase = w * 14;
            float a3u = __shfl_up(p[3], 16, 64);        // alpha of row-1 for e==0
            float a0d = __shfl_down(p[0], 16, 64);      // alpha of row+1 for e==3
            float wpv[4], wnv[4];
            #pragma unroll
            for (int e = 0; e < 4; e++) {
                const int jr = gg * 4 + e;
                const int nl = n0 - 1 + jbase + jr;     // within-graph node idx
                const bool hp = nl >= 1;
                const bool hn = nl < NLEN - 1;
                float ap = (e > 0) ? p[e - 1] : a3u;
                float an = (e < 3) ? p[e + 1] : a0d;
                float apx = hp ? ap : -1e30f;
                float anx = hn ? an : -1e30f;
                float mx = fmaxf(apx, anx);
                float ep = hp ? __expf(ap - mx) : 0.f;
                float en = hn ? __expf(an - mx) : 0.f;
                float inv = 1.f / (ep + en + 1e-16f);
                wpv[e] = ep * inv; wnv[e] = en * inv;
            }
            #pragma unroll
            for (int q = 0; q < HT; q++) {
                float v0, v1, v2, v3;
                if constexpr (MPACK) {
                    v0 = bf16_to_f((unsigned short)(mpk[q][0] & 0xffff));
                    v1 = bf16_to_f((unsigned short)(mpk[q][0] >> 16));
                    v2 = bf16_to_f((unsigned short)(mpk[q][1] & 0xffff));
                    v3 = bf16_to_f((unsigned short)(mpk[q][1] >> 16));
                } else {
                    v0 = mf[q][0]; v1 = mf[q][1]; v2 = mf[q][2]; v3 = mf[q][3];
                }
                float m3u = __shfl_up(v3, 16, 64);      // M[row-1] for e==0
                float m0d = __shfl_down(v0, 16, 64);    // M[row+1] for e==3
                float mvals[4] = {v0, v1, v2, v3};
                #pragma unroll
                for (int e = 0; e < 4; e++) {
                    float mprev = (e > 0) ? mvals[e - 1] : m3u;
                    float mnext = (e < 3) ? mvals[e + 1] : m0d;
                    out[q][e] += wpv[e] * mprev + wnv[e] * mnext;
                }
            }
        }
    }

    // ---- self-loop tiles + finalize + store ----
    #pragma unroll
    for (int q2 = 0; q2 < HT; q2++) {
        const int nt  = MT + q2;
        const int cur = nt & 1;
        const int ntn = nt + 1;
        const bool doStage = (ntn < NTOT);
        f32x4 sreg[CHPT];
        if (doStage) {
            const f32x4* ps = (const f32x4*)pw + (size_t)ntn * NCH;
            #pragma unroll
            for (int i = 0; i < CHPT; i++) { int idx = tid + i * 256; if (idx < NCH) sreg[i] = ps[idx]; }
        }
        const int c2  = q2 * 16 + r;
        const float bsv = bs[c2];
        short8 bh[KC], bl[KC];
        #pragma unroll
        for (int kc = 0; kc < KC; kc++) {
            bh[kc] = *(const short8*)&bufs[cur][(kc * 2 + 0) * 512 + boff];
            bl[kc] = *(const short8*)&bufs[cur][(kc * 2 + 1) * 512 + boff];
        }
        f32x4 acc = {bsv, bsv, bsv, bsv};
        #pragma unroll
        for (int kc = 0; kc < KC; kc++) {
            acc = __builtin_amdgcn_mfma_f32_16x16x32_bf16(a_hi[kc], bh[kc], acc, 0, 0, 0);
            acc = __builtin_amdgcn_mfma_f32_16x16x32_bf16(a_hi[kc], bl[kc], acc, 0, 0, 0);
            acc = __builtin_amdgcn_mfma_f32_16x16x32_bf16(a_lo[kc], bh[kc], acc, 0, 0, 0);
        }
        const int jbase = w * 14;
        #pragma unroll
        for (int e = 0; e < 4; e++) {
            const int jr = gg * 4 + e;
            const int nl = n0 - 1 + jbase + jr;
            float v = out[q2][e] * invH + acc[e];
            v = v > 0.f ? v : __expf(v) - 1.f;          // ELU (layers 1..4)
            if (jr >= 1 && jr <= 14 && nl < NLEN)
                y[(gstart + nl) * COUT + c2] = v;
        }
        if (doStage) {
            const int nb = ntn & 1;
            #pragma unroll
            for (int i = 0; i < CHPT; i++) { int idx = tid + i * 256; if (idx < NCH) *(f32x4*)&bufs[nb][idx * 8] = sreg[i]; }
        }
        __syncthreads();
    }
}

// Layer 5 + head at the last node per graph (single incoming edge -> softmax weight 1).
__global__ void final_head(const float* __restrict__ x4,   // [NUMV][64]
                           const float* __restrict__ Wm,   // [64][32]
                           const float* __restrict__ bm,
                           const float* __restrict__ Ws,   // [64][32]
                           const float* __restrict__ bs,
                           const float* __restrict__ Wc,   // [32][1]
                           const float* __restrict__ bc,
                           float* __restrict__ out)        // [32] ++ [32*32]
{
    int g = blockIdx.x;
    int c = threadIdx.x;
    const float* xu = &x4[((long)g * NLEN + NLEN - 2) * 64];
    const float* xv = xu + 64;
    float o = 0.f;
    if (c < 32) {
        float m = bm[c];
        float s = bs[c];
        for (int k = 0; k < 64; k++) {
            m = fmaf(xu[k], Wm[k * 32 + c], m);
            s = fmaf(xv[k], Ws[k * 32 + c], s);
        }
        m = m > 0.f ? m : 0.01f * m;
        o = m + s;
        out[32 + g * 32 + c] = o;
    }
    float tsum = (c < 32) ? o * Wc[c] : 0.f;
    #pragma unroll
    for (int sft = 16; sft > 0; sft >>= 1)
        tsum += __shfl_xor(tsum, sft, 64);
    if (c == 0) out[g] = tsum + bc[0];
}

extern "C" void kernel_launch(void* const* d_in, const int* in_sizes, int n_in,
                              void* d_out, int out_size, void* d_ws, size_t ws_size,
                              hipStream_t stream)
{
    const float* nodes = (const float*)d_in[0];
    auto L = [&](int l, int k) { return (const float*)d_in[1 + (l - 1) * 5 + k]; };

    float* xb0 = (float*)d_ws;                       // [NUMV][128] f32
    float* xb1 = xb0 + (size_t)NUMV * 128;
    unsigned short* p1 = (unsigned short*)(xb1 + (size_t)NUMV * 128);
    unsigned short* p2 = p1 + 72 * 1024;             // L1: NT=72, KC=1
    unsigned short* p3 = p2 + 72 * 4096;             // L2: NT=72, KC=4
    unsigned short* p4 = p3 + 68 * 4096;             // L3: NT=68, KC=4
                                                     // L4: NT=68, KC=2

    pack_all<<<dim3(512), dim3(256), 0, stream>>>(
        L(1,0), L(1,2), L(2,0), L(2,2), L(3,0), L(3,2), L(4,0), L(4,2), p1, p2, p3, p4);

    constexpr int TPG = (NLEN + 55) / 56;            // 19
    dim3 grid(BATCH * TPG);                          // 608 blocks
    dim3 blk(256);

    conv_reg<1,   128, 8,  false><<<grid, blk, 0, stream>>>(nodes, p1, L(1,1), L(1,3), L(1,4), xb0);
    conv_reg<128, 128, 8,  true ><<<grid, blk, 0, stream>>>(xb0,   p2, L(2,1), L(2,3), L(2,4), xb1);
    conv_reg<128, 64,  16, false><<<grid, blk, 0, stream>>>(xb1,   p3, L(3,1), L(3,3), L(3,4), xb0);
    conv_reg<64,  64,  16, false><<<grid, blk, 0, stream>>>(xb0,   p4, L(4,1), L(4,3), L(4,4), xb1);

    final_head<<<dim3(BATCH), dim3(64), 0, stream>>>(
        xb1, L(5,0), L(5,1), L(5,2), L(5,3),
        (const float*)d_in[26], (const float*)d_in[27], (float*)d_out);
}